// Round 1
// baseline (3814.463 us; speedup 1.0000x reference)
//
#include <hip/hip_runtime.h>
#include <hip/hip_fp16.h>

// ---------------------------------------------------------------------------
// FFT-conv1d: B=8, C_in=256, C_out=256, L=8192, K=4096, padding='same'
// Overlap-save with FFT order F=8192: 2 blocks, 4097 valid outputs each.
// out[b,o,n] = sum_{i,k} w[o,i,k] * x[b,i,n+k-2047]   (cross-correlation)
// Pipeline:
//   K1 wfft  : per (o,i) rfft_8192(w pad) -> conj -> fp16  [o][i][pl][f]
//   K2 xfft  : per (n=blk*8+b, i) rfft_8192(segment)->fp16 [n][i][pl][f]
//   K3 xtr   : x_f -> MFMA-B-fragment layout [f][pl][ioct][n][e8]
//   K4 einsum: per bin complex GEMM [256o x 256i] x [256i x 16n] (f16 MFMA)
//              writes conv_f fp32 [f][pl][o][n]
//   K5 ctr   : transpose -> convT fp32 [o][n][pl][f]
//   K6 irfft : inverse rfft_8192 + bias -> out[b][o][pos]
// ---------------------------------------------------------------------------

#define NBP 4128   // 4097 bins padded to 4128 (129 chunks of 32)

typedef _Float16 half8_ __attribute__((ext_vector_type(8)));
typedef float float4_ __attribute__((ext_vector_type(4)));

__device__ __forceinline__ float2 cadd(float2 a, float2 b){ return make_float2(a.x+b.x, a.y+b.y); }
__device__ __forceinline__ float2 csub(float2 a, float2 b){ return make_float2(a.x-b.x, a.y-b.y); }
__device__ __forceinline__ float2 cmul(float2 a, float2 b){ return make_float2(a.x*b.x - a.y*b.y, a.x*b.y + a.y*b.x); }

__device__ __forceinline__ int rev8_4(int v) {
  return ((v & 7) << 9) | (((v >> 3) & 7) << 6) | (((v >> 6) & 7) << 3) | ((v >> 9) & 7);
}

__device__ __forceinline__ void dft8(const float2 a[8], float2 b[8]) {
  const float r = 0.70710678118654752f;
  // even part (a0,a2,a4,a6)
  float2 t0 = cadd(a[0], a[4]), t1 = csub(a[0], a[4]);
  float2 t2 = cadd(a[2], a[6]), t3 = csub(a[2], a[6]);
  float2 E0 = cadd(t0, t2), E2 = csub(t0, t2);
  float2 E1 = make_float2(t1.x + t3.y, t1.y - t3.x);   // t1 - i*t3
  float2 E3 = make_float2(t1.x - t3.y, t1.y + t3.x);   // t1 + i*t3
  // odd part (a1,a3,a5,a7)
  float2 u0 = cadd(a[1], a[5]), u1 = csub(a[1], a[5]);
  float2 u2 = cadd(a[3], a[7]), u3 = csub(a[3], a[7]);
  float2 O0 = cadd(u0, u2), O2 = csub(u0, u2);
  float2 O1 = make_float2(u1.x + u3.y, u1.y - u3.x);
  float2 O3 = make_float2(u1.x - u3.y, u1.y + u3.x);
  // O1 *= w8^1 = (r,-r); O2 *= -i; O3 *= w8^3 = (-r,-r)
  O1 = make_float2(r*(O1.x + O1.y), r*(O1.y - O1.x));
  O2 = make_float2(O2.y, -O2.x);
  O3 = make_float2(r*(O3.y - O3.x), -r*(O3.x + O3.y));
  b[0] = cadd(E0, O0); b[4] = csub(E0, O0);
  b[1] = cadd(E1, O1); b[5] = csub(E1, O1);
  b[2] = cadd(E2, O2); b[6] = csub(E2, O2);
  b[3] = cadd(E3, O3); b[7] = csub(E3, O3);
}

// In-place radix-8 DIF complex FFT, 4096 points, 128 threads.
// Output is base-8 digit-reversed: X[f] ends at sh[rev8_4(f)].
__device__ void fft4096(float2* sh, int tid) {
  #pragma unroll
  for (int s = 0; s < 4; ++s) {
    const int ls = 9 - 3*s;         // log2(m); m = 512,64,8,1
    const int m = 1 << ls;
    const int n = m << 3;
    __syncthreads();
    #pragma unroll
    for (int u = 0; u < 4; ++u) {
      int idx = tid + (u << 7);      // 0..511
      int sb = idx >> ls;
      int q  = idx & (m - 1);
      int base = (sb << (ls + 3)) + q;
      float2 a[8], b[8];
      #pragma unroll
      for (int j = 0; j < 8; ++j) a[j] = sh[base + (j << ls)];
      dft8(a, b);
      float sn, cs;
      __sincosf(-6.2831853071795864f * (float)q / (float)n, &sn, &cs);
      float2 w1 = make_float2(cs, sn);
      float2 wc = make_float2(1.f, 0.f);
      sh[base] = b[0];
      #pragma unroll
      for (int j = 1; j < 8; ++j) { wc = cmul(wc, w1); sh[base + (j << ls)] = cmul(b[j], wc); }
    }
  }
  __syncthreads();
}

// ---------------- K1: weight FFT -------------------------------------------
// w: [o][i][4096] fp32 ;  wf: [pair=o*256+i][pl 2][NBP] fp16 (conjugated)
__global__ __launch_bounds__(128) void wfft_kernel(const float* __restrict__ w,
                                                   __half* __restrict__ wf) {
  __shared__ float2 sh[4096];
  const int pair = blockIdx.x;
  const int tid = threadIdx.x;
  const float2* wp2 = reinterpret_cast<const float2*>(w + (size_t)pair * 4096);
  for (int t = tid; t < 2048; t += 128) sh[t] = wp2[t];             // z[t]=(w[2t],w[2t+1])
  for (int t = 2048 + tid; t < 4096; t += 128) sh[t] = make_float2(0.f, 0.f);
  fft4096(sh, tid);
  __half* out_re = wf + (size_t)pair * (2 * NBP);
  __half* out_im = out_re + NBP;
  for (int f = tid; f <= 4096; f += 128) {
    int fa = f & 4095, fb = (4096 - f) & 4095;
    float2 Zf = sh[rev8_4(fa)], Zc = sh[rev8_4(fb)];
    float2 Fe = make_float2(0.5f*(Zf.x + Zc.x), 0.5f*(Zf.y - Zc.y));
    float2 Fd = make_float2(0.5f*(Zf.x - Zc.x), 0.5f*(Zf.y + Zc.y));
    float2 Fo = make_float2(Fd.y, -Fd.x);                           // Fd / i
    float sn, cs;
    __sincosf(-7.66990393942820427e-4f * (float)f, &sn, &cs);       // -pi*f/4096
    float2 R = cadd(Fe, cmul(make_float2(cs, sn), Fo));
    out_re[f] = __float2half(R.x);
    out_im[f] = __float2half(-R.y);                                 // conj
  }
  for (int f = 4097 + tid; f < NBP; f += 128) { out_re[f] = __float2half(0.f); out_im[f] = __float2half(0.f); }
}

// ---------------- K2: x FFT ------------------------------------------------
// x: [b][i][8192] fp32 ; xf0: [n=blk*8+b][i][pl][NBP] fp16
__global__ __launch_bounds__(128) void xfft_kernel(const float* __restrict__ x,
                                                   __half* __restrict__ xf0) {
  __shared__ float2 sh[4096];
  const int tr = blockIdx.x;           // n*256 + i
  const int n = tr >> 8, i = tr & 255;
  const int blk = n >> 3, b = n & 7;
  const int tid = threadIdx.x;
  const float* xp = x + ((size_t)b * 256 + i) * 8192;
  const int off = blk ? 2050 : -2047;  // s[t] = x[t+off] (bounds-checked)
  for (int t = tid; t < 4096; t += 128) {
    int a0 = 2*t + off, a1 = 2*t + 1 + off;
    float v0 = (a0 >= 0 && a0 < 8192) ? xp[a0] : 0.f;
    float v1 = (a1 >= 0 && a1 < 8192) ? xp[a1] : 0.f;
    sh[t] = make_float2(v0, v1);
  }
  fft4096(sh, tid);
  __half* out_re = xf0 + ((size_t)n * 256 + i) * (2 * NBP);
  __half* out_im = out_re + NBP;
  for (int f = tid; f <= 4096; f += 128) {
    int fa = f & 4095, fb = (4096 - f) & 4095;
    float2 Zf = sh[rev8_4(fa)], Zc = sh[rev8_4(fb)];
    float2 Fe = make_float2(0.5f*(Zf.x + Zc.x), 0.5f*(Zf.y - Zc.y));
    float2 Fd = make_float2(0.5f*(Zf.x - Zc.x), 0.5f*(Zf.y + Zc.y));
    float2 Fo = make_float2(Fd.y, -Fd.x);
    float sn, cs;
    __sincosf(-7.66990393942820427e-4f * (float)f, &sn, &cs);
    float2 R = cadd(Fe, cmul(make_float2(cs, sn), Fo));
    out_re[f] = __float2half(R.x);
    out_im[f] = __float2half(R.y);                                  // no conj
  }
  for (int f = 4097 + tid; f < NBP; f += 128) { out_re[f] = __float2half(0.f); out_im[f] = __float2half(0.f); }
}

// ---------------- K3: x_f -> B-fragment layout -----------------------------
// xf0: [n16][i256][pl2][NBP]  ->  xF: [f NBP][pl2][ioct32][n16][e8] fp16
__global__ __launch_bounds__(256) void xtr_kernel(const __half* __restrict__ xf0,
                                                  __half* __restrict__ xF) {
  __shared__ __half tile[16 * 32 * 2 * 8];   // [n][i_loc][pl][f_loc 8] = 16KB
  const int nfc = NBP / 8;                   // 516
  const int f0 = (blockIdx.x % nfc) * 8;
  const int ic = blockIdx.x / nfc;           // 0..7 (i-chunk of 32)
  const int i0 = ic * 32;
  const int tid = threadIdx.x;
  for (int r = tid; r < 1024; r += 256) {    // (n, i_loc, pl)
    int pl = r & 1, i_loc = (r >> 1) & 31, n = r >> 6;
    const __half* src = xf0 + (((size_t)n * 256 + i0 + i_loc) * 2 + pl) * NBP + f0;
    uint4 v = *reinterpret_cast<const uint4*>(src);
    *reinterpret_cast<uint4*>(&tile[(((n * 32 + i_loc) * 2) + pl) * 8]) = v;
  }
  __syncthreads();
  const ushort* tu = reinterpret_cast<const ushort*>(tile);
  for (int u = tid; u < 1024; u += 256) {    // (fl, pl, ioct_loc, n)
    int n = u & 15, io = (u >> 4) & 3, pl = (u >> 6) & 1, fl = u >> 7;
    ushort tmp[8];
    #pragma unroll
    for (int e = 0; e < 8; ++e)
      tmp[e] = tu[(((n * 32 + io * 8 + e) * 2) + pl) * 8 + fl];
    size_t dst = ((((size_t)(f0 + fl) * 2 + pl) * 32 + (ic * 4 + io)) * 16 + n) * 8;
    *reinterpret_cast<uint4*>(xF + dst) = *reinterpret_cast<uint4*>(tmp);
  }
}

// ---------------- K4: frequency-domain einsum ------------------------------
// wf: [o*256+i][pl][NBP]  xF: [f][pl][ioct][n][e8]  -> convf fp32 [f][pl][o256][n16]
__global__ __launch_bounds__(256) void einsum_kernel(const __half* __restrict__ wf,
                                                     const __half* __restrict__ xF,
                                                     float* __restrict__ convf) {
  __shared__ __half wst[32 * 2 * 16 * 32];   // [bin][pl][o16][i32] = 64KB
  const int fc = blockIdx.x >> 4;            // 0..128
  const int ot = blockIdx.x & 15;
  const int f0 = fc * 32, o0 = ot * 16;
  const int tid = threadIdx.x;
  const int wv = tid >> 6, lane = tid & 63;
  const int lo = lane & 15, lq = lane >> 4;

  float4_ acc[8][2];
  #pragma unroll
  for (int bb = 0; bb < 8; ++bb) { acc[bb][0] = (float4_)0.f; acc[bb][1] = (float4_)0.f; }

  for (int ks = 0; ks < 8; ++ks) {           // k-slices of 32 over i
    __syncthreads();
    for (int r = tid; r < 1024; r += 256) {  // (o, i_loc, pl): 64B each
      int pl = r & 1, i_loc = (r >> 1) & 15, o = r >> 5;   // i_loc here = pair-of... decompose below
      // re-decompose: 16 o x 32 i x 2 pl = 1024 runs
      o = r >> 6; int il = (r >> 1) & 31; pl = r & 1;
      const __half* src = wf + ((((size_t)(o0 + o) * 256) + (ks * 32 + il)) * 2 + pl) * NBP + f0;
      const uint4* s4 = reinterpret_cast<const uint4*>(src);
      uint4 d[4];
      d[0] = s4[0]; d[1] = s4[1]; d[2] = s4[2]; d[3] = s4[3];
      const __half* hh = reinterpret_cast<const __half*>(d);
      #pragma unroll
      for (int bb = 0; bb < 32; ++bb)
        wst[((bb * 2 + pl) * 16 + o) * 32 + il] = hh[bb];
    }
    __syncthreads();
    #pragma unroll
    for (int bb = 0; bb < 8; ++bb) {
      const int bin = wv * 8 + bb;
      const int f = f0 + bin;
      half8_ Are = *reinterpret_cast<const half8_*>(&wst[((bin * 2 + 0) * 16 + lo) * 32 + lq * 8]);
      half8_ Aim = *reinterpret_cast<const half8_*>(&wst[((bin * 2 + 1) * 16 + lo) * 32 + lq * 8]);
      const __half* bp = xF + ((((size_t)f * 2 + 0) * 32 + (ks * 4 + lq)) * 16 + lo) * 8;
      half8_ Bre = *reinterpret_cast<const half8_*>(bp);
      half8_ Bim = *reinterpret_cast<const half8_*>(bp + (size_t)32 * 16 * 8);
      half8_ nAim = -Aim;
      acc[bb][0] = __builtin_amdgcn_mfma_f32_16x16x32_f16(Are,  Bre, acc[bb][0], 0, 0, 0);
      acc[bb][0] = __builtin_amdgcn_mfma_f32_16x16x32_f16(nAim, Bim, acc[bb][0], 0, 0, 0);
      acc[bb][1] = __builtin_amdgcn_mfma_f32_16x16x32_f16(Are,  Bim, acc[bb][1], 0, 0, 0);
      acc[bb][1] = __builtin_amdgcn_mfma_f32_16x16x32_f16(Aim,  Bre, acc[bb][1], 0, 0, 0);
    }
  }
  // epilogue: conv_f[f][pl][o][n], C/D: col n = lane&15, row o = (lane>>4)*4 + r
  #pragma unroll
  for (int bb = 0; bb < 8; ++bb) {
    const int f = f0 + wv * 8 + bb;
    #pragma unroll
    for (int pl = 0; pl < 2; ++pl) {
      #pragma unroll
      for (int r = 0; r < 4; ++r) {
        int o = o0 + lq * 4 + r;
        convf[(((size_t)f * 2 + pl) * 256 + o) * 16 + lo] = acc[bb][pl][r];
      }
    }
  }
}

// ---------------- K5: conv spectrum transpose ------------------------------
// convf [f][pl][o][n] fp32 -> convT [o][n][pl][f] fp32
__global__ __launch_bounds__(256) void ctr_kernel(const float* __restrict__ cf,
                                                  float* __restrict__ cT) {
  __shared__ float tile[16 * 2 * 16 * 16];   // [fl][pl][o][n] = 32KB
  const int nfc = NBP / 16;                  // 258
  const int f0 = (blockIdx.x % nfc) * 16;
  const int o0 = (blockIdx.x / nfc) * 16;
  const int tid = threadIdx.x;
  for (int r = tid; r < 512; r += 256) {     // (fl, pl, o): 64B each
    int o = r & 15, pl = (r >> 4) & 1, fl = r >> 5;
    const float* src = cf + (((size_t)(f0 + fl) * 2 + pl) * 256 + (o0 + o)) * 16;
    float* dst = &tile[((fl * 2 + pl) * 16 + o) * 16];
    #pragma unroll
    for (int k = 0; k < 4; ++k)
      *reinterpret_cast<float4*>(dst + 4 * k) = *reinterpret_cast<const float4*>(src + 4 * k);
  }
  __syncthreads();
  for (int u = tid; u < 512; u += 256) {     // (o, n, pl): 64B each
    int pl = u & 1, n = (u >> 1) & 15, o = u >> 5;
    float tmp[16];
    #pragma unroll
    for (int fl = 0; fl < 16; ++fl) tmp[fl] = tile[((fl * 2 + pl) * 16 + o) * 16 + n];
    float* dst = cT + (((size_t)(o0 + o) * 16 + n) * 2 + pl) * NBP + f0;
    #pragma unroll
    for (int k = 0; k < 4; ++k)
      *reinterpret_cast<float4*>(dst + 4 * k) = *reinterpret_cast<const float4*>(tmp + 4 * k);
  }
}

// ---------------- K6: inverse FFT + bias + store ---------------------------
// convT [o][n][pl][NBP] fp32 -> out [b][o][8192] fp32
__global__ __launch_bounds__(128) void irfft_kernel(const float* __restrict__ cT,
                                                    const float* __restrict__ bias,
                                                    float* __restrict__ out) {
  __shared__ float2 sh[4096];
  const int tr = blockIdx.x;                 // o*16 + n
  const int o = tr >> 4, n = tr & 15;
  const int blk = n >> 3, b = n & 7;
  const int tid = threadIdx.x;
  const float* Rre = cT + (((size_t)o * 16 + n) * 2 + 0) * NBP;
  const float* Rim = Rre + NBP;
  for (int f = tid; f < 4096; f += 128) {
    int fb = 4096 - f;                       // bin 4096 exists
    float2 Rf  = make_float2(Rre[f],  Rim[f]);
    float2 Rcj = make_float2(Rre[fb], -Rim[fb]);
    float2 Fe = make_float2(0.5f*(Rf.x + Rcj.x), 0.5f*(Rf.y + Rcj.y));
    float2 Fd = make_float2(0.5f*(Rf.x - Rcj.x), 0.5f*(Rf.y - Rcj.y));
    float sn, cs;
    __sincosf(7.66990393942820427e-4f * (float)f, &sn, &cs);  // +pi*f/4096
    float2 Fo = cmul(make_float2(cs, sn), Fd);
    // Z = Fe + i*Fo ; store conj(Z)
    sh[f] = make_float2(Fe.x - Fo.y, -(Fe.y + Fo.x));
  }
  fft4096(sh, tid);
  const float bi = bias[o];
  const int n0 = blk * 4097;
  const int mmax = blk ? 4095 : 4097;
  const float inv = 1.0f / 4096.0f;
  float* op = out + ((size_t)b * 256 + o) * 8192 + n0;
  for (int t = tid; t < 4096; t += 128) {
    float2 X = sh[rev8_4(t)];
    float r0 =  X.x * inv + bi;
    float r1 = -X.y * inv + bi;
    int m0 = 2 * t, m1 = 2 * t + 1;
    if (m0 < mmax) op[m0] = r0;
    if (m1 < mmax) op[m1] = r1;
  }
}

// ---------------------------------------------------------------------------
extern "C" void kernel_launch(void* const* d_in, const int* in_sizes, int n_in,
                              void* d_out, int out_size, void* d_ws, size_t ws_size,
                              hipStream_t stream) {
  (void)in_sizes; (void)n_in; (void)out_size; (void)ws_size;
  const float* x    = (const float*)d_in[0];
  const float* w    = (const float*)d_in[1];
  const float* bias = (const float*)d_in[2];
  float* out = (float*)d_out;

  char* ws = (char*)d_ws;
  size_t off = 0;
  __half* wf = (__half*)(ws + off);   off += (size_t)65536 * 2 * NBP * 2;        // 1.082 GB
  __half* xF = (__half*)(ws + off);   off += (size_t)NBP * 2 * 32 * 16 * 8 * 2;  // 67.6 MB
  float* convf = (float*)(ws + off);  off += (size_t)NBP * 2 * 256 * 16 * 4;     // 135.3 MB
  // shared region: xf0 (phase 1) and convT (phase 2) — disjoint in time
  __half* xf0 = (__half*)(ws + off);
  float*  cT  = (float*)(ws + off);   // needs 135.3 MB

  wfft_kernel  <<<dim3(65536),        dim3(128), 0, stream>>>(w, wf);
  xfft_kernel  <<<dim3(4096),         dim3(128), 0, stream>>>(x, xf0);
  xtr_kernel   <<<dim3((NBP/8) * 8),  dim3(256), 0, stream>>>(xf0, xF);
  einsum_kernel<<<dim3(129 * 16),     dim3(256), 0, stream>>>(wf, xF, convf);
  ctr_kernel   <<<dim3((NBP/16) * 16),dim3(256), 0, stream>>>(convf, cT);
  irfft_kernel <<<dim3(4096),         dim3(128), 0, stream>>>(cT, bias, out);
}